// Round 1
// baseline (352.787 us; speedup 1.0000x reference)
//
#include <hip/hip_runtime.h>
#include <hip/hip_bf16.h>

#define NN   5000
#define NE   80000
#define HID  128
#define NRBF 64
#define PI_OVER_5 0.6283185307179586f
#define LN_EPS 1e-5f

typedef unsigned short bf16_t;

__device__ __forceinline__ bf16_t to_bf16(float x){
    union { float f; unsigned int u; } v; v.f = x;
    unsigned int r = v.u + 0x7fffu + ((v.u >> 16) & 1u);
    return (bf16_t)(r >> 16);
}
__device__ __forceinline__ float from_bf16(bf16_t h){
    union { unsigned int u; float f; } v; v.u = ((unsigned int)h) << 16;
    return v.f;
}

// ---------------------------------------------------------------- embL/embR
// embL[t][h] = sum_k W_emb2[h][k]      * emb[t][k]
// embR[t][h] = sum_k W_emb2[h][128+k]  * emb[t][k]
__global__ __launch_bounds__(128) void k_embtab(
    const float* __restrict__ W_emb2, const float* __restrict__ emb,
    float* __restrict__ embL, float* __restrict__ embR)
{
    int t = blockIdx.x;   // atom type
    int h = threadIdx.x;  // channel
    const float* er = emb + t * HID;
    const float* wl = W_emb2 + (size_t)h * (2 * HID);
    float sl = 0.f, sr = 0.f;
    #pragma unroll 8
    for (int k = 0; k < HID; k++){
        float e = er[k];
        sl += wl[k] * e;
        sr += wl[HID + k] * e;
    }
    embL[t * HID + h] = sl;
    embR[t * HID + h] = sr;
}

// ---------------------------------------------------------------- CSR build
__global__ void k_count(const int* __restrict__ ei, int* __restrict__ counts){
    int e = blockIdx.x * 256 + threadIdx.x;
    if (e < NE) atomicAdd(&counts[ei[e]], 1);
}

__global__ __launch_bounds__(1024) void k_scan(
    const int* __restrict__ counts, int* __restrict__ offsets, int* __restrict__ cursor)
{
    __shared__ int s[1024];
    const int t = threadIdx.x;
    const int CH = 5;            // 1024*5 >= 5000
    int base = t * CH;
    int loc[CH];
    int lsum = 0;
    #pragma unroll
    for (int u = 0; u < CH; u++){
        int i = base + u;
        int v = (i < NN) ? counts[i] : 0;
        loc[u] = lsum;           // local exclusive prefix
        lsum += v;
    }
    s[t] = lsum;
    __syncthreads();
    for (int d = 1; d < 1024; d <<= 1){
        int v = (t >= d) ? s[t - d] : 0;
        __syncthreads();
        s[t] += v;
        __syncthreads();
    }
    int excl = s[t] - lsum;
    #pragma unroll
    for (int u = 0; u < CH; u++){
        int i = base + u;
        if (i < NN){ int o = excl + loc[u]; offsets[i] = o; cursor[i] = o; }
    }
    if (t == 1023) offsets[NN] = s[1023];
}

__global__ void k_fill(const int* __restrict__ ei, int* __restrict__ cursor,
                       int* __restrict__ elist){
    int e = blockIdx.x * 256 + threadIdx.x;
    if (e < NE){
        int p = atomicAdd(&cursor[ei[e]], 1);
        elist[p] = e;
    }
}

// ---------------------------------------------------------------- edge phase
// Per 64-edge x 128-h tile: C = cut * (embL[zs] + embR[zd] + b_emb2);
// f_i = (attr @ Wd_i^T + bd_i) * C  -> bf16
__global__ __launch_bounds__(256) void k_edge(
    const int* __restrict__ z, const int* __restrict__ ei,
    const float* __restrict__ ew, const float* __restrict__ attr,
    const float* __restrict__ embL, const float* __restrict__ embR,
    const float* __restrict__ b_emb2,
    const float* __restrict__ Wd1, const float* __restrict__ bd1,
    const float* __restrict__ Wd2, const float* __restrict__ bd2,
    const float* __restrict__ Wd3, const float* __restrict__ bd3,
    bf16_t* __restrict__ f1, bf16_t* __restrict__ f2, bf16_t* __restrict__ f3)
{
    __shared__ float sA[64][68];    // attr tile, pad for conflicts + f4 align
    __shared__ float sW[128][65];   // Wd tile, odd stride -> conflict-free scalar
    __shared__ float sCut[64];
    __shared__ int   sZs[64], sZd[64];

    const int tid = threadIdx.x;
    const int e0  = blockIdx.x * 64;

    // stage attr tile (64 x 64 f32)
    {
        int r = tid >> 2, q = tid & 3;
        const float* ar = attr + (size_t)(e0 + r) * NRBF + q * 16;
        float4 v0 = *(const float4*)(ar + 0);
        float4 v1 = *(const float4*)(ar + 4);
        float4 v2 = *(const float4*)(ar + 8);
        float4 v3 = *(const float4*)(ar + 12);
        *(float4*)&sA[r][q * 16 + 0]  = v0;
        *(float4*)&sA[r][q * 16 + 4]  = v1;
        *(float4*)&sA[r][q * 16 + 8]  = v2;
        *(float4*)&sA[r][q * 16 + 12] = v3;
    }
    if (tid < 64){
        int e = e0 + tid;
        sZs[tid] = z[ei[e]];
        sZd[tid] = z[ei[NE + e]];
        float w = ew[e];
        float c = (w < 5.0f) ? 0.5f * (__cosf(w * PI_OVER_5) + 1.0f) : 0.0f;
        sCut[tid] = c;
    }
    __syncthreads();

    const int te = tid >> 4, th = tid & 15;
    const int hb = th * 8;

    // C micro-tile: 4 edges x 8 channels
    float be[8];
    {
        const float* bp = b_emb2 + hb;
        float4 b0 = *(const float4*)bp, b1 = *(const float4*)(bp + 4);
        be[0]=b0.x; be[1]=b0.y; be[2]=b0.z; be[3]=b0.w;
        be[4]=b1.x; be[5]=b1.y; be[6]=b1.z; be[7]=b1.w;
    }
    float C[4][8];
    #pragma unroll
    for (int i = 0; i < 4; i++){
        int el = te * 4 + i;
        int zs = sZs[el], zd = sZd[el];
        float cv = sCut[el];
        const float* Lp = embL + zs * HID + hb;
        const float* Rp = embR + zd * HID + hb;
        float4 l0 = *(const float4*)Lp, l1 = *(const float4*)(Lp + 4);
        float4 r0 = *(const float4*)Rp, r1 = *(const float4*)(Rp + 4);
        C[i][0] = cv * (l0.x + r0.x + be[0]);
        C[i][1] = cv * (l0.y + r0.y + be[1]);
        C[i][2] = cv * (l0.z + r0.z + be[2]);
        C[i][3] = cv * (l0.w + r0.w + be[3]);
        C[i][4] = cv * (l1.x + r1.x + be[4]);
        C[i][5] = cv * (l1.y + r1.y + be[5]);
        C[i][6] = cv * (l1.z + r1.z + be[6]);
        C[i][7] = cv * (l1.w + r1.w + be[7]);
    }

    const float* Wds[3] = {Wd1, Wd2, Wd3};
    const float* bds[3] = {bd1, bd2, bd3};
    bf16_t* fs[3] = {f1, f2, f3};

    #pragma unroll
    for (int w = 0; w < 3; w++){
        // stage Wd_w (128 x 64) -- global f4 loads, scalar LDS writes (stride 65)
        {
            int hr = tid >> 1, half = tid & 1;
            const float* wr = Wds[w] + (size_t)hr * NRBF + half * 32;
            float4 v[8];
            #pragma unroll
            for (int c4 = 0; c4 < 8; c4++) v[c4] = *(const float4*)(wr + c4 * 4);
            __syncthreads();   // prior k-loop reads done before overwrite
            float* srow = &sW[hr][half * 32];
            #pragma unroll
            for (int c4 = 0; c4 < 8; c4++){
                srow[c4*4+0] = v[c4].x; srow[c4*4+1] = v[c4].y;
                srow[c4*4+2] = v[c4].z; srow[c4*4+3] = v[c4].w;
            }
            __syncthreads();
        }
        float g[4][8];
        #pragma unroll
        for (int i = 0; i < 4; i++)
            #pragma unroll
            for (int j = 0; j < 8; j++) g[i][j] = 0.f;

        #pragma unroll 4
        for (int k = 0; k < NRBF; k++){
            float a0 = sA[te*4+0][k];
            float a1 = sA[te*4+1][k];
            float a2 = sA[te*4+2][k];
            float a3 = sA[te*4+3][k];
            #pragma unroll
            for (int j = 0; j < 8; j++){
                float wv = sW[hb + j][k];
                g[0][j] += a0 * wv;
                g[1][j] += a1 * wv;
                g[2][j] += a2 * wv;
                g[3][j] += a3 * wv;
            }
        }
        // epilogue: f = (g + bd) * C
        float bdv[8];
        {
            const float* bp = bds[w] + hb;
            float4 b0 = *(const float4*)bp, b1 = *(const float4*)(bp + 4);
            bdv[0]=b0.x; bdv[1]=b0.y; bdv[2]=b0.z; bdv[3]=b0.w;
            bdv[4]=b1.x; bdv[5]=b1.y; bdv[6]=b1.z; bdv[7]=b1.w;
        }
        #pragma unroll
        for (int i = 0; i < 4; i++){
            bf16_t* dst = fs[w] + (size_t)(e0 + te * 4 + i) * HID + hb;
            #pragma unroll
            for (int j = 0; j < 8; j++){
                dst[j] = to_bf16((g[i][j] + bdv[j]) * C[i][j]);
            }
        }
    }
}

// ---------------------------------------------------------------- gather + LN
// acc planes: 0:c 1:ax 2:ay 3:az 4:sxx 5:syy 6:szz 7:sxy 8:sxz 9:syz
__global__ __launch_bounds__(128) void k_gather(
    const int* __restrict__ offsets, const int* __restrict__ elist,
    const float* __restrict__ evn,
    const bf16_t* __restrict__ f1, const bf16_t* __restrict__ f2, const bf16_t* __restrict__ f3,
    const float* __restrict__ ln_g, const float* __restrict__ ln_b,
    float* __restrict__ acc, float* __restrict__ ln_out)
{
    const int n = blockIdx.x, h = threadIdx.x;
    const int s = offsets[n], e_end = offsets[n + 1];
    float c=0, ax=0, ay=0, az=0, sxx=0, syy=0, szz=0, sxy=0, sxz=0, syz=0;
    for (int idx = s; idx < e_end; idx++){
        int e = elist[idx];
        float vx = evn[e*3+0], vy = evn[e*3+1], vz = evn[e*3+2];
        float t3 = (vx*vx + vy*vy + vz*vz) * (1.f/3.f);
        float a = from_bf16(f1[(size_t)e * HID + h]);
        float b = from_bf16(f2[(size_t)e * HID + h]);
        float d = from_bf16(f3[(size_t)e * HID + h]);
        c += a;
        ax += b * vx; ay += b * vy; az += b * vz;
        sxx += d * (vx*vx - t3); syy += d * (vy*vy - t3); szz += d * (vz*vz - t3);
        sxy += d * (vx*vy); sxz += d * (vx*vz); syz += d * (vy*vz);
    }
    const int NH = NN * HID;
    const int base = n * HID + h;
    acc[0*NH+base]=c;   acc[1*NH+base]=ax;  acc[2*NH+base]=ay;  acc[3*NH+base]=az;
    acc[4*NH+base]=sxx; acc[5*NH+base]=syy; acc[6*NH+base]=szz;
    acc[7*NH+base]=sxy; acc[8*NH+base]=sxz; acc[9*NH+base]=syz;

    float tn = 3.f*c*c + 2.f*c*(sxx+syy+szz)
             + sxx*sxx + syy*syy + szz*szz
             + 2.f*(sxy*sxy + sxz*sxz + syz*syz)
             + 2.f*(ax*ax + ay*ay + az*az);

    __shared__ float r1[128], r2[128];
    r1[h] = tn; r2[h] = tn * tn;
    __syncthreads();
    for (int st = 64; st > 0; st >>= 1){
        if (h < st){ r1[h] += r1[h + st]; r2[h] += r2[h + st]; }
        __syncthreads();
    }
    float mu  = r1[0] * (1.f / HID);
    float var = r2[0] * (1.f / HID) - mu * mu;
    ln_out[base] = (tn - mu) * rsqrtf(var + LN_EPS) * ln_g[h] + ln_b[h];
}

// ---------------------------------------------------------------- generic GEMM
// out[M x Nc] = act(A[M x K] @ W[Nc x K]^T + bias)
template<int SILU, int BIAS>
__device__ __forceinline__ void gemm_body(
    const float* __restrict__ A, const float* __restrict__ W,
    const float* __restrict__ bias, float* __restrict__ out,
    int M, int K, int Nc)
{
    __shared__ float sA[64][36];
    __shared__ float sW[64][33];
    const int tid = threadIdx.x;
    const int tm = tid >> 4, tn = tid & 15;
    const int m0 = blockIdx.x * 64, n0 = blockIdx.y * 64;
    const int r = tid >> 2, q = tid & 3;
    float acc[4][4] = {{0.f}};

    for (int k0 = 0; k0 < K; k0 += 32){
        float4 a0, a1;
        int m = m0 + r;
        if (m < M){
            const float* ap = A + (size_t)m * K + k0 + q * 8;
            a0 = *(const float4*)ap; a1 = *(const float4*)(ap + 4);
        } else {
            a0 = make_float4(0.f,0.f,0.f,0.f); a1 = a0;
        }
        const float* wp = W + (size_t)(n0 + r) * K + k0 + q * 8;
        float4 w0 = *(const float4*)wp, w1 = *(const float4*)(wp + 4);
        __syncthreads();
        *(float4*)&sA[r][q * 8]     = a0;
        *(float4*)&sA[r][q * 8 + 4] = a1;
        float* wrow = &sW[r][q * 8];
        wrow[0]=w0.x; wrow[1]=w0.y; wrow[2]=w0.z; wrow[3]=w0.w;
        wrow[4]=w1.x; wrow[5]=w1.y; wrow[6]=w1.z; wrow[7]=w1.w;
        __syncthreads();
        #pragma unroll 8
        for (int k = 0; k < 32; k++){
            float av[4], wv[4];
            #pragma unroll
            for (int i = 0; i < 4; i++) av[i] = sA[tm*4+i][k];
            #pragma unroll
            for (int j = 0; j < 4; j++) wv[j] = sW[tn*4+j][k];
            #pragma unroll
            for (int i = 0; i < 4; i++)
                #pragma unroll
                for (int j = 0; j < 4; j++)
                    acc[i][j] += av[i] * wv[j];
        }
    }
    #pragma unroll
    for (int i = 0; i < 4; i++){
        int m = m0 + tm * 4 + i;
        if (m >= M) continue;
        #pragma unroll
        for (int j = 0; j < 4; j++){
            int nn = n0 + tn * 4 + j;
            float v = acc[i][j];
            if (BIAS) v += bias[nn];
            if (SILU) v = v / (1.f + __expf(-v));
            out[(size_t)m * Nc + nn] = v;
        }
    }
}

__global__ __launch_bounds__(256) void k_mlp1(
    const float* __restrict__ A, const float* __restrict__ W,
    const float* __restrict__ b, float* __restrict__ out)
{
    gemm_body<1,1>(A, W, b, out, NN, 128, 256);
}
__global__ __launch_bounds__(256) void k_mlp2(
    const float* __restrict__ A, const float* __restrict__ W,
    const float* __restrict__ b, float* __restrict__ out)
{
    gemm_body<1,1>(A, W, b, out, NN, 256, 384);
}
__global__ __launch_bounds__(256) void k_mix(
    const float* __restrict__ acc, const float* __restrict__ Wt1,
    const float* __restrict__ Wt2, const float* __restrict__ Wt3,
    float* __restrict__ tmp)
{
    int p = blockIdx.z;
    const float* W = (p == 0) ? Wt1 : ((p < 4) ? Wt2 : Wt3);
    gemm_body<0,0>(acc + (size_t)p * NN * HID, W, nullptr,
                   tmp + (size_t)p * NN * HID, NN, 128, 128);
}

// ---------------------------------------------------------------- output
__global__ __launch_bounds__(256) void k_out(
    const float* __restrict__ tmp, const float* __restrict__ norm,
    float* __restrict__ out)
{
    int i = blockIdx.x * 256 + threadIdx.x;   // n*128 + g
    if (i >= NN * HID) return;
    int n = i >> 7, g = i & 127;
    const int NH = NN * HID;
    float c   = tmp[i];
    float ax  = tmp[1*NH+i], ay = tmp[2*NH+i], az = tmp[3*NH+i];
    float sxx = tmp[4*NH+i], syy= tmp[5*NH+i], szz= tmp[6*NH+i];
    float sxy = tmp[7*NH+i], sxz= tmp[8*NH+i], syz= tmp[9*NH+i];
    const float* nr = norm + (size_t)n * 384 + g * 3;
    float n0 = nr[0], n1 = nr[1], n2 = nr[2];
    float* o = out + (size_t)i * 9;
    o[0] = n0*c + n2*sxx;  o[1] = n2*sxy - n1*az;  o[2] = n2*sxz + n1*ay;
    o[3] = n2*sxy + n1*az; o[4] = n0*c + n2*syy;   o[5] = n2*syz - n1*ax;
    o[6] = n2*sxz - n1*ay; o[7] = n2*syz + n1*ax;  o[8] = n0*c + n2*szz;
}

// ---------------------------------------------------------------- launch
extern "C" void kernel_launch(void* const* d_in, const int* in_sizes, int n_in,
                              void* d_out, int out_size, void* d_ws, size_t ws_size,
                              hipStream_t stream)
{
    (void)in_sizes; (void)n_in; (void)out_size; (void)ws_size;
    const int*   z      = (const int*)  d_in[0];
    const int*   ei     = (const int*)  d_in[1];
    const float* ew     = (const float*)d_in[2];
    const float* evn    = (const float*)d_in[3];
    const float* attr   = (const float*)d_in[4];
    const float* emb    = (const float*)d_in[5];
    const float* W_emb2 = (const float*)d_in[6];
    const float* b_emb2 = (const float*)d_in[7];
    const float* Wd1 = (const float*)d_in[8];  const float* bd1 = (const float*)d_in[9];
    const float* Wd2 = (const float*)d_in[10]; const float* bd2 = (const float*)d_in[11];
    const float* Wd3 = (const float*)d_in[12]; const float* bd3 = (const float*)d_in[13];
    const float* Wt1 = (const float*)d_in[14]; const float* Wt2 = (const float*)d_in[15];
    const float* Wt3 = (const float*)d_in[16];
    const float* Ws1 = (const float*)d_in[17]; const float* bs1 = (const float*)d_in[18];
    const float* Ws2 = (const float*)d_in[19]; const float* bs2 = (const float*)d_in[20];
    const float* ln_g = (const float*)d_in[21]; const float* ln_b = (const float*)d_in[22];
    float* out = (float*)d_out;

    char* ws = (char*)d_ws;
    size_t o = 0;
    auto take = [&](size_t b)->size_t{ size_t c = o; o += (b + 255) & ~(size_t)255; return c; };
    size_t f1_o  = take((size_t)NE * HID * 2);
    size_t f2_o  = take((size_t)NE * HID * 2);
    size_t f3_o  = take((size_t)NE * HID * 2);
    size_t acc_o = take((size_t)10 * NN * HID * 4);
    size_t ln_of = take((size_t)NN * HID * 4);
    size_t h1_o  = take((size_t)NN * 256 * 4);
    size_t nrm_o = take((size_t)NN * 384 * 4);
    size_t eL_o  = take((size_t)128 * HID * 4);
    size_t eR_o  = take((size_t)128 * HID * 4);
    size_t cnt_o = take((size_t)NN * 4);
    size_t off_o = take((size_t)(NN + 1) * 4);
    size_t cur_o = take((size_t)NN * 4);
    size_t el_o  = take((size_t)NE * 4);

    bf16_t* f1 = (bf16_t*)(ws + f1_o);
    bf16_t* f2 = (bf16_t*)(ws + f2_o);
    bf16_t* f3 = (bf16_t*)(ws + f3_o);
    float* accb = (float*)(ws + acc_o);
    float* lnb  = (float*)(ws + ln_of);
    float* h1b  = (float*)(ws + h1_o);
    float* nrmb = (float*)(ws + nrm_o);
    float* embL = (float*)(ws + eL_o);
    float* embR = (float*)(ws + eR_o);
    int* counts = (int*)(ws + cnt_o);
    int* offs   = (int*)(ws + off_o);
    int* cursor = (int*)(ws + cur_o);
    int* elist  = (int*)(ws + el_o);
    float* tmpb = (float*)(ws + f1_o);   // alias: f1/f2 dead after k_gather

    hipMemsetAsync(counts, 0, (size_t)NN * 4, stream);

    k_embtab<<<128, 128, 0, stream>>>(W_emb2, emb, embL, embR);
    k_count <<<(NE + 255) / 256, 256, 0, stream>>>(ei, counts);
    k_scan  <<<1, 1024, 0, stream>>>(counts, offs, cursor);
    k_fill  <<<(NE + 255) / 256, 256, 0, stream>>>(ei, cursor, elist);
    k_edge  <<<NE / 64, 256, 0, stream>>>(z, ei, ew, attr, embL, embR, b_emb2,
                                          Wd1, bd1, Wd2, bd2, Wd3, bd3, f1, f2, f3);
    k_gather<<<NN, 128, 0, stream>>>(offs, elist, evn, f1, f2, f3, ln_g, ln_b, accb, lnb);
    k_mlp1  <<<dim3((NN + 63) / 64, 4, 1), 256, 0, stream>>>(lnb, Ws1, bs1, h1b);
    k_mlp2  <<<dim3((NN + 63) / 64, 6, 1), 256, 0, stream>>>(h1b, Ws2, bs2, nrmb);
    k_mix   <<<dim3((NN + 63) / 64, 2, 10), 256, 0, stream>>>(accb, Wt1, Wt2, Wt3, tmpb);
    k_out   <<<(NN * HID + 255) / 256, 256, 0, stream>>>(tmpb, nrmb, out);
}

// Round 2
// 285.227 us; speedup vs baseline: 1.2369x; 1.2369x over previous
//
#include <hip/hip_runtime.h>
#include <hip/hip_bf16.h>

#define NN   5000
#define NE   80000
#define HID  128
#define NRBF 64
#define PI_OVER_5 0.6283185307179586f
#define LN_EPS 1e-5f

typedef unsigned short bf16_t;
typedef __attribute__((ext_vector_type(8))) short short8;
typedef __attribute__((ext_vector_type(4))) float floatx4;

__device__ __forceinline__ bf16_t to_bf16(float x){
    union { float f; unsigned int u; } v; v.f = x;
    unsigned int r = v.u + 0x7fffu + ((v.u >> 16) & 1u);
    return (bf16_t)(r >> 16);
}
__device__ __forceinline__ float from_bf16(bf16_t h){
    union { unsigned int u; float f; } v; v.u = ((unsigned int)h) << 16;
    return v.f;
}

// ---------------------------------------------------------------- embL/embR
__global__ __launch_bounds__(128) void k_embtab(
    const float* __restrict__ W_emb2, const float* __restrict__ emb,
    float* __restrict__ embL, float* __restrict__ embR)
{
    int t = blockIdx.x;
    int h = threadIdx.x;
    const float* er = emb + t * HID;
    const float* wl = W_emb2 + (size_t)h * (2 * HID);
    float sl = 0.f, sr = 0.f;
    #pragma unroll 8
    for (int k = 0; k < HID; k++){
        float e = er[k];
        sl += wl[k] * e;
        sr += wl[HID + k] * e;
    }
    embL[t * HID + h] = sl;
    embR[t * HID + h] = sr;
}

// ---------------------------------------------------------------- weight prep
// Wcat[384][64] bf16 (rows: t*128+ch), bdcat[384] f32
__global__ __launch_bounds__(256) void k_prep_w(
    const float* __restrict__ Wd1, const float* __restrict__ Wd2, const float* __restrict__ Wd3,
    const float* __restrict__ bd1, const float* __restrict__ bd2, const float* __restrict__ bd3,
    bf16_t* __restrict__ Wcat, float* __restrict__ bdcat)
{
    int t = blockIdx.x * 256 + threadIdx.x;   // 3072 threads, 8 elems each
    int idx = t * 8;
    int row = idx >> 6;         // 0..383
    int tb  = row >> 7;         // table
    int ch  = row & 127;
    const float* W = (tb == 0) ? Wd1 : ((tb == 1) ? Wd2 : Wd3);
    const float* s = W + (size_t)ch * NRBF + (idx & 63);
    float4 a = *(const float4*)s;
    float4 b = *(const float4*)(s + 4);
    uint4 o;
    o.x = to_bf16(a.x) | ((unsigned)to_bf16(a.y) << 16);
    o.y = to_bf16(a.z) | ((unsigned)to_bf16(a.w) << 16);
    o.z = to_bf16(b.x) | ((unsigned)to_bf16(b.y) << 16);
    o.w = to_bf16(b.z) | ((unsigned)to_bf16(b.w) << 16);
    *(uint4*)(Wcat + idx) = o;
    if (t < 384){
        int tb2 = t >> 7, ch2 = t & 127;
        const float* bsrc = (tb2 == 0) ? bd1 : ((tb2 == 1) ? bd2 : bd3);
        bdcat[t] = bsrc[ch2];
    }
}

// ---------------------------------------------------------------- CSR build
__global__ void k_count(const int* __restrict__ ei, int* __restrict__ counts){
    int e = blockIdx.x * 256 + threadIdx.x;
    if (e < NE) atomicAdd(&counts[ei[e]], 1);
}

__global__ __launch_bounds__(1024) void k_scan(
    const int* __restrict__ counts, int* __restrict__ offsets, int* __restrict__ cursor)
{
    __shared__ int s[1024];
    const int t = threadIdx.x;
    const int CH = 5;
    int base = t * CH;
    int loc[CH];
    int lsum = 0;
    #pragma unroll
    for (int u = 0; u < CH; u++){
        int i = base + u;
        int v = (i < NN) ? counts[i] : 0;
        loc[u] = lsum;
        lsum += v;
    }
    s[t] = lsum;
    __syncthreads();
    for (int d = 1; d < 1024; d <<= 1){
        int v = (t >= d) ? s[t - d] : 0;
        __syncthreads();
        s[t] += v;
        __syncthreads();
    }
    int excl = s[t] - lsum;
    #pragma unroll
    for (int u = 0; u < CH; u++){
        int i = base + u;
        if (i < NN){ int o = excl + loc[u]; offsets[i] = o; cursor[i] = o; }
    }
    if (t == 1023) offsets[NN] = s[1023];
}

// fill: also pre-permute cut/zpack and edge_vec into CSR position order
__global__ void k_fill(const int* __restrict__ ei, const int* __restrict__ z,
                       const float* __restrict__ ew, const float* __restrict__ evn,
                       int* __restrict__ cursor, int* __restrict__ elist,
                       float2* __restrict__ meta, float* __restrict__ evn_p){
    int e = blockIdx.x * 256 + threadIdx.x;
    if (e < NE){
        int sN = ei[e], dN = ei[NE + e];
        int p = atomicAdd(&cursor[sN], 1);
        elist[p] = e;
        float w = ew[e];
        float c = (w < 5.0f) ? 0.5f * (__cosf(w * PI_OVER_5) + 1.0f) : 0.0f;
        meta[p] = make_float2(c, __int_as_float(z[sN] | (z[dN] << 8)));
        evn_p[p*3+0] = evn[e*3+0];
        evn_p[p*3+1] = evn[e*3+1];
        evn_p[p*3+2] = evn[e*3+2];
    }
}

// gather attr rows into CSR order, converted to bf16: attrb[p][64]
__global__ __launch_bounds__(256) void k_prep_attr(
    const float* __restrict__ attr, const int* __restrict__ elist,
    bf16_t* __restrict__ attrb)
{
    int t = blockIdx.x * 256 + threadIdx.x;   // one thread per 8 elements
    int r = t >> 3;
    if (r >= NE) return;
    int e = elist[r];
    const float* src = attr + (size_t)e * NRBF + (t & 7) * 8;
    float4 a = *(const float4*)src;
    float4 b = *(const float4*)(src + 4);
    uint4 o;
    o.x = to_bf16(a.x) | ((unsigned)to_bf16(a.y) << 16);
    o.y = to_bf16(a.z) | ((unsigned)to_bf16(a.w) << 16);
    o.z = to_bf16(b.x) | ((unsigned)to_bf16(b.y) << 16);
    o.w = to_bf16(b.z) | ((unsigned)to_bf16(b.w) << 16);
    *(uint4*)(attrb + (size_t)r * NRBF + (t & 7) * 8) = o;
}

// ---------------------------------------------------------------- edge MFMA
// GEMM: out[ch=384][e] = sum_k Wcat[ch][k] * attrb[e][k], then
// f_t[p][ch] = (out + bd) * cut*(embL[zs]+embR[zd]+b_emb2), bf16 store.
// A-operand = Wcat rows (M=384), B-operand = attr rows (N=64 edges/block).
// D layout: col(lane&15)=edge, row((lane>>4)*4+reg)=channel  [m89/m91]
__global__ __launch_bounds__(256) void k_edge(
    const bf16_t* __restrict__ attrb, const float2* __restrict__ meta,
    const bf16_t* __restrict__ Wcat, const float* __restrict__ bdcat,
    const float* __restrict__ embL, const float* __restrict__ embR,
    const float* __restrict__ b_emb2,
    bf16_t* __restrict__ f1, bf16_t* __restrict__ f2, bf16_t* __restrict__ f3)
{
    // 64 rows x (64+8) shorts: row stride 144B -> 2-way max bank aliasing
    __shared__ __align__(16) bf16_t sB[64 * 72];
    __shared__ float sCut[64];
    __shared__ int   sZ[64];

    const int tid = threadIdx.x;
    const int p0  = blockIdx.x * 64;

    // stage attr tile (64 x 64 bf16 = 8KB), 2 chunks of 16B per thread
    #pragma unroll
    for (int i = 0; i < 2; i++){
        int cID = tid * 2 + i;          // 0..511
        int r = cID >> 3, c = cID & 7;
        uint4 v = *(const uint4*)(attrb + (size_t)(p0 + r) * NRBF + c * 8);
        *(uint4*)&sB[r * 72 + c * 8] = v;
    }
    if (tid < 64){
        float2 m = meta[p0 + tid];
        sCut[tid] = m.x;
        sZ[tid]   = __float_as_int(m.y);
    }
    __syncthreads();

    const int wv = tid >> 6, lane = tid & 63;
    const int col = lane & 15, q = lane >> 4;

    floatx4 acc[6][4];
    #pragma unroll
    for (int mt = 0; mt < 6; mt++)
        #pragma unroll
        for (int nt = 0; nt < 4; nt++)
            acc[mt][nt] = (floatx4)(0.f);

    #pragma unroll
    for (int s = 0; s < 2; s++){
        short8 bf[4];
        #pragma unroll
        for (int nt = 0; nt < 4; nt++){
            int r = nt * 16 + col;
            bf[nt] = *(const short8*)&sB[r * 72 + s * 32 + q * 8];
        }
        short8 af[6];
        #pragma unroll
        for (int t = 0; t < 3; t++)
            #pragma unroll
            for (int c = 0; c < 2; c++){
                int m = t * 128 + wv * 32 + c * 16 + col;
                af[t * 2 + c] = *(const short8*)(Wcat + (size_t)m * NRBF + s * 32 + q * 8);
            }
        #pragma unroll
        for (int mt = 0; mt < 6; mt++)
            #pragma unroll
            for (int nt = 0; nt < 4; nt++)
                acc[mt][nt] = __builtin_amdgcn_mfma_f32_16x16x32_bf16(
                    af[mt], bf[nt], acc[mt][nt], 0, 0, 0);
    }

    // epilogue
    floatx4 be[2], bd[3][2];
    #pragma unroll
    for (int c = 0; c < 2; c++){
        int ch4 = wv * 32 + c * 16 + q * 4;
        be[c] = *(const floatx4*)(b_emb2 + ch4);
        #pragma unroll
        for (int t = 0; t < 3; t++)
            bd[t][c] = *(const floatx4*)(bdcat + t * 128 + ch4);
    }
    bf16_t* const fs[3] = {f1, f2, f3};
    #pragma unroll
    for (int nt = 0; nt < 4; nt++){
        int e = nt * 16 + col;
        float cut = sCut[e];
        int zp = sZ[e];
        int zs = zp & 255, zd = zp >> 8;
        size_t orow = (size_t)(p0 + e) * HID;
        #pragma unroll
        for (int c = 0; c < 2; c++){
            int ch4 = wv * 32 + c * 16 + q * 4;
            floatx4 L = *(const floatx4*)(embL + zs * HID + ch4);
            floatx4 R = *(const floatx4*)(embR + zd * HID + ch4);
            floatx4 Cv = (L + R + be[c]) * cut;
            #pragma unroll
            for (int t = 0; t < 3; t++){
                floatx4 v = (acc[t * 2 + c][nt] + bd[t][c]) * Cv;
                uint2 pk;
                pk.x = to_bf16(v[0]) | ((unsigned)to_bf16(v[1]) << 16);
                pk.y = to_bf16(v[2]) | ((unsigned)to_bf16(v[3]) << 16);
                *(uint2*)(fs[t] + orow + ch4) = pk;
            }
        }
    }
}

// ---------------------------------------------------------------- gather + LN
__global__ __launch_bounds__(128) void k_gather(
    const int* __restrict__ offsets, const float* __restrict__ evn_p,
    const bf16_t* __restrict__ f1, const bf16_t* __restrict__ f2, const bf16_t* __restrict__ f3,
    const float* __restrict__ ln_g, const float* __restrict__ ln_b,
    float* __restrict__ acc, float* __restrict__ ln_out)
{
    const int n = blockIdx.x, h = threadIdx.x;
    const int s = offsets[n], e_end = offsets[n + 1];
    float c=0, ax=0, ay=0, az=0, sxx=0, syy=0, szz=0, sxy=0, sxz=0, syz=0;
    for (int idx = s; idx < e_end; idx++){
        float vx = evn_p[idx*3+0], vy = evn_p[idx*3+1], vz = evn_p[idx*3+2];
        float t3 = (vx*vx + vy*vy + vz*vz) * (1.f/3.f);
        float a = from_bf16(f1[(size_t)idx * HID + h]);
        float b = from_bf16(f2[(size_t)idx * HID + h]);
        float d = from_bf16(f3[(size_t)idx * HID + h]);
        c += a;
        ax += b * vx; ay += b * vy; az += b * vz;
        sxx += d * (vx*vx - t3); syy += d * (vy*vy - t3); szz += d * (vz*vz - t3);
        sxy += d * (vx*vy); sxz += d * (vx*vz); syz += d * (vy*vz);
    }
    const int NH = NN * HID;
    const int base = n * HID + h;
    acc[0*NH+base]=c;   acc[1*NH+base]=ax;  acc[2*NH+base]=ay;  acc[3*NH+base]=az;
    acc[4*NH+base]=sxx; acc[5*NH+base]=syy; acc[6*NH+base]=szz;
    acc[7*NH+base]=sxy; acc[8*NH+base]=sxz; acc[9*NH+base]=syz;

    float tn = 3.f*c*c + 2.f*c*(sxx+syy+szz)
             + sxx*sxx + syy*syy + szz*szz
             + 2.f*(sxy*sxy + sxz*sxz + syz*syz)
             + 2.f*(ax*ax + ay*ay + az*az);

    __shared__ float r1[128], r2[128];
    r1[h] = tn; r2[h] = tn * tn;
    __syncthreads();
    for (int st = 64; st > 0; st >>= 1){
        if (h < st){ r1[h] += r1[h + st]; r2[h] += r2[h + st]; }
        __syncthreads();
    }
    float mu  = r1[0] * (1.f / HID);
    float var = r2[0] * (1.f / HID) - mu * mu;
    ln_out[base] = (tn - mu) * rsqrtf(var + LN_EPS) * ln_g[h] + ln_b[h];
}

// ---------------------------------------------------------------- generic GEMM
template<int SILU, int BIAS>
__device__ __forceinline__ void gemm_body(
    const float* __restrict__ A, const float* __restrict__ W,
    const float* __restrict__ bias, float* __restrict__ out,
    int M, int K, int Nc)
{
    __shared__ float sA[64][36];
    __shared__ float sW[64][33];
    const int tid = threadIdx.x;
    const int tm = tid >> 4, tn = tid & 15;
    const int m0 = blockIdx.x * 64, n0 = blockIdx.y * 64;
    const int r = tid >> 2, q = tid & 3;
    float acc[4][4] = {{0.f}};

    for (int k0 = 0; k0 < K; k0 += 32){
        float4 a0, a1;
        int m = m0 + r;
        if (m < M){
            const float* ap = A + (size_t)m * K + k0 + q * 8;
            a0 = *(const float4*)ap; a1 = *(const float4*)(ap + 4);
        } else {
            a0 = make_float4(0.f,0.f,0.f,0.f); a1 = a0;
        }
        const float* wp = W + (size_t)(n0 + r) * K + k0 + q * 8;
        float4 w0 = *(const float4*)wp, w1 = *(const float4*)(wp + 4);
        __syncthreads();
        *(float4*)&sA[r][q * 8]     = a0;
        *(float4*)&sA[r][q * 8 + 4] = a1;
        float* wrow = &sW[r][q * 8];
        wrow[0]=w0.x; wrow[1]=w0.y; wrow[2]=w0.z; wrow[3]=w0.w;
        wrow[4]=w1.x; wrow[5]=w1.y; wrow[6]=w1.z; wrow[7]=w1.w;
        __syncthreads();
        #pragma unroll 8
        for (int k = 0; k < 32; k++){
            float av[4], wv[4];
            #pragma unroll
            for (int i = 0; i < 4; i++) av[i] = sA[tm*4+i][k];
            #pragma unroll
            for (int j = 0; j < 4; j++) wv[j] = sW[tn*4+j][k];
            #pragma unroll
            for (int i = 0; i < 4; i++)
                #pragma unroll
                for (int j = 0; j < 4; j++)
                    acc[i][j] += av[i] * wv[j];
        }
    }
    #pragma unroll
    for (int i = 0; i < 4; i++){
        int m = m0 + tm * 4 + i;
        if (m >= M) continue;
        #pragma unroll
        for (int j = 0; j < 4; j++){
            int nn = n0 + tn * 4 + j;
            float v = acc[i][j];
            if (BIAS) v += bias[nn];
            if (SILU) v = v / (1.f + __expf(-v));
            out[(size_t)m * Nc + nn] = v;
        }
    }
}

__global__ __launch_bounds__(256) void k_mlp1(
    const float* __restrict__ A, const float* __restrict__ W,
    const float* __restrict__ b, float* __restrict__ out)
{
    gemm_body<1,1>(A, W, b, out, NN, 128, 256);
}
__global__ __launch_bounds__(256) void k_mlp2(
    const float* __restrict__ A, const float* __restrict__ W,
    const float* __restrict__ b, float* __restrict__ out)
{
    gemm_body<1,1>(A, W, b, out, NN, 256, 384);
}
__global__ __launch_bounds__(256) void k_mix(
    const float* __restrict__ acc, const float* __restrict__ Wt1,
    const float* __restrict__ Wt2, const float* __restrict__ Wt3,
    float* __restrict__ tmp)
{
    int p = blockIdx.z;
    const float* W = (p == 0) ? Wt1 : ((p < 4) ? Wt2 : Wt3);
    gemm_body<0,0>(acc + (size_t)p * NN * HID, W, nullptr,
                   tmp + (size_t)p * NN * HID, NN, 128, 128);
}

// ---------------------------------------------------------------- output
__global__ __launch_bounds__(256) void k_out(
    const float* __restrict__ tmp, const float* __restrict__ norm,
    float* __restrict__ out)
{
    int i = blockIdx.x * 256 + threadIdx.x;
    if (i >= NN * HID) return;
    int n = i >> 7, g = i & 127;
    const int NH = NN * HID;
    float c   = tmp[i];
    float ax  = tmp[1*NH+i], ay = tmp[2*NH+i], az = tmp[3*NH+i];
    float sxx = tmp[4*NH+i], syy= tmp[5*NH+i], szz= tmp[6*NH+i];
    float sxy = tmp[7*NH+i], sxz= tmp[8*NH+i], syz= tmp[9*NH+i];
    const float* nr = norm + (size_t)n * 384 + g * 3;
    float n0 = nr[0], n1 = nr[1], n2 = nr[2];
    float* o = out + (size_t)i * 9;
    o[0] = n0*c + n2*sxx;  o[1] = n2*sxy - n1*az;  o[2] = n2*sxz + n1*ay;
    o[3] = n2*sxy + n1*az; o[4] = n0*c + n2*syy;   o[5] = n2*syz - n1*ax;
    o[6] = n2*sxz - n1*ay; o[7] = n2*syz + n1*ax;  o[8] = n0*c + n2*szz;
}

// ---------------------------------------------------------------- launch
extern "C" void kernel_launch(void* const* d_in, const int* in_sizes, int n_in,
                              void* d_out, int out_size, void* d_ws, size_t ws_size,
                              hipStream_t stream)
{
    (void)in_sizes; (void)n_in; (void)out_size; (void)ws_size;
    const int*   z      = (const int*)  d_in[0];
    const int*   ei     = (const int*)  d_in[1];
    const float* ew     = (const float*)d_in[2];
    const float* evn    = (const float*)d_in[3];
    const float* attr   = (const float*)d_in[4];
    const float* emb    = (const float*)d_in[5];
    const float* W_emb2 = (const float*)d_in[6];
    const float* b_emb2 = (const float*)d_in[7];
    const float* Wd1 = (const float*)d_in[8];  const float* bd1 = (const float*)d_in[9];
    const float* Wd2 = (const float*)d_in[10]; const float* bd2 = (const float*)d_in[11];
    const float* Wd3 = (const float*)d_in[12]; const float* bd3 = (const float*)d_in[13];
    const float* Wt1 = (const float*)d_in[14]; const float* Wt2 = (const float*)d_in[15];
    const float* Wt3 = (const float*)d_in[16];
    const float* Ws1 = (const float*)d_in[17]; const float* bs1 = (const float*)d_in[18];
    const float* Ws2 = (const float*)d_in[19]; const float* bs2 = (const float*)d_in[20];
    const float* ln_g = (const float*)d_in[21]; const float* ln_b = (const float*)d_in[22];
    float* out = (float*)d_out;

    char* ws = (char*)d_ws;
    size_t o = 0;
    auto take = [&](size_t b)->size_t{ size_t c = o; o += (b + 255) & ~(size_t)255; return c; };
    size_t f1_o  = take((size_t)NE * HID * 2);
    size_t f2_o  = take((size_t)NE * HID * 2);
    size_t f3_o  = take((size_t)NE * HID * 2);
    size_t acc_o = take((size_t)10 * NN * HID * 4);   // attrb aliases front of this
    size_t ln_of = take((size_t)NN * HID * 4);
    size_t h1_o  = take((size_t)NN * 256 * 4);
    size_t nrm_o = take((size_t)NN * 384 * 4);
    size_t eL_o  = take((size_t)128 * HID * 4);
    size_t eR_o  = take((size_t)128 * HID * 4);
    size_t cnt_o = take((size_t)NN * 4);
    size_t off_o = take((size_t)(NN + 1) * 4);
    size_t cur_o = take((size_t)NN * 4);
    size_t el_o  = take((size_t)NE * 4);
    size_t met_o = take((size_t)NE * 8);
    size_t evp_o = take((size_t)NE * 12);
    size_t wc_o  = take((size_t)384 * 64 * 2);
    size_t bdc_o = take((size_t)384 * 4);

    bf16_t* f1 = (bf16_t*)(ws + f1_o);
    bf16_t* f2 = (bf16_t*)(ws + f2_o);
    bf16_t* f3 = (bf16_t*)(ws + f3_o);
    float* accb = (float*)(ws + acc_o);
    bf16_t* attrb = (bf16_t*)(ws + acc_o);   // alias: dead before k_gather writes acc
    float* lnb  = (float*)(ws + ln_of);
    float* h1b  = (float*)(ws + h1_o);
    float* nrmb = (float*)(ws + nrm_o);
    float* embL = (float*)(ws + eL_o);
    float* embR = (float*)(ws + eR_o);
    int* counts = (int*)(ws + cnt_o);
    int* offs   = (int*)(ws + off_o);
    int* cursor = (int*)(ws + cur_o);
    int* elist  = (int*)(ws + el_o);
    float2* meta = (float2*)(ws + met_o);
    float* evn_p = (float*)(ws + evp_o);
    bf16_t* Wcat = (bf16_t*)(ws + wc_o);
    float* bdcat = (float*)(ws + bdc_o);
    float* tmpb = (float*)(ws + f1_o);   // alias: f1/f2 dead after k_gather

    hipMemsetAsync(counts, 0, (size_t)NN * 4, stream);

    k_prep_w<<<12, 256, 0, stream>>>(Wd1, Wd2, Wd3, bd1, bd2, bd3, Wcat, bdcat);
    k_embtab<<<128, 128, 0, stream>>>(W_emb2, emb, embL, embR);
    k_count <<<(NE + 255) / 256, 256, 0, stream>>>(ei, counts);
    k_scan  <<<1, 1024, 0, stream>>>(counts, offs, cursor);
    k_fill  <<<(NE + 255) / 256, 256, 0, stream>>>(ei, z, ew, evn, cursor, elist, meta, evn_p);
    k_prep_attr<<<(NE * 8) / 256, 256, 0, stream>>>(attr, elist, attrb);
    k_edge  <<<NE / 64, 256, 0, stream>>>(attrb, meta, Wcat, bdcat, embL, embR, b_emb2,
                                          f1, f2, f3);
    k_gather<<<NN, 128, 0, stream>>>(offs, evn_p, f1, f2, f3, ln_g, ln_b, accb, lnb);
    k_mlp1  <<<dim3((NN + 63) / 64, 4, 1), 256, 0, stream>>>(lnb, Ws1, bs1, h1b);
    k_mlp2  <<<dim3((NN + 63) / 64, 6, 1), 256, 0, stream>>>(h1b, Ws2, bs2, nrmb);
    k_mix   <<<dim3((NN + 63) / 64, 2, 10), 256, 0, stream>>>(accb, Wt1, Wt2, Wt3, tmpb);
    k_out   <<<(NN * HID + 255) / 256, 256, 0, stream>>>(tmpb, nrmb, out);
}

// Round 3
// 229.804 us; speedup vs baseline: 1.5352x; 1.2412x over previous
//
#include <hip/hip_runtime.h>
#include <hip/hip_bf16.h>

#define NN   5000
#define NP   5008          // NN padded to 16
#define NE   80000
#define HID  128
#define NRBF 64
#define PI_OVER_5 0.6283185307179586f
#define LN_EPS 1e-5f

typedef unsigned short bf16_t;
typedef __attribute__((ext_vector_type(8))) short short8;
typedef __attribute__((ext_vector_type(4))) float floatx4;

__device__ __forceinline__ bf16_t to_bf16(float x){
    union { float f; unsigned int u; } v; v.f = x;
    unsigned int r = v.u + 0x7fffu + ((v.u >> 16) & 1u);
    return (bf16_t)(r >> 16);
}
__device__ __forceinline__ float from_bf16(bf16_t h){
    union { unsigned int u; float f; } v; v.u = ((unsigned int)h) << 16;
    return v.f;
}
__device__ __forceinline__ uint4 pack8(const float* s){
    float4 a = *(const float4*)s;
    float4 b = *(const float4*)(s + 4);
    uint4 o;
    o.x = to_bf16(a.x) | ((unsigned)to_bf16(a.y) << 16);
    o.y = to_bf16(a.z) | ((unsigned)to_bf16(a.w) << 16);
    o.z = to_bf16(b.x) | ((unsigned)to_bf16(b.y) << 16);
    o.w = to_bf16(b.z) | ((unsigned)to_bf16(b.w) << 16);
    return o;
}

// ---------------------------------------------------------------- embL/embR
__global__ __launch_bounds__(128) void k_embtab(
    const float* __restrict__ W_emb2, const float* __restrict__ emb,
    float* __restrict__ embL, float* __restrict__ embR)
{
    int t = blockIdx.x;
    int h = threadIdx.x;
    const float* er = emb + t * HID;
    const float* wl = W_emb2 + (size_t)h * (2 * HID);
    float sl = 0.f, sr = 0.f;
    #pragma unroll 8
    for (int k = 0; k < HID; k++){
        float e = er[k];
        sl += wl[k] * e;
        sr += wl[HID + k] * e;
    }
    embL[t * HID + h] = sl;
    embR[t * HID + h] = sr;
}

// ---------------------------------------------------------------- weight prep
// Wcat[384][64], Wtc[3][128][128], Ws1b[256][128], Ws2b[384][256] (bf16), bdcat[384] f32
__global__ __launch_bounds__(256) void k_prep_wts(
    const float* __restrict__ Wd1, const float* __restrict__ Wd2, const float* __restrict__ Wd3,
    const float* __restrict__ bd1, const float* __restrict__ bd2, const float* __restrict__ bd3,
    const float* __restrict__ Wt1, const float* __restrict__ Wt2, const float* __restrict__ Wt3,
    const float* __restrict__ Ws1, const float* __restrict__ Ws2,
    bf16_t* __restrict__ Wcat, bf16_t* __restrict__ Wtc,
    bf16_t* __restrict__ Ws1b, bf16_t* __restrict__ Ws2b, float* __restrict__ bdcat)
{
    int t = blockIdx.x * 256 + threadIdx.x;     // 25600 threads
    int i8 = t * 8;
    const float* src; bf16_t* dst;
    if (i8 < 24576){
        int j = i8; int tb = j >> 13; int r = j & 8191;
        src = ((tb == 0) ? Wd1 : (tb == 1) ? Wd2 : Wd3) + r; dst = Wcat + j;
    } else if (i8 < 24576 + 49152){
        int j = i8 - 24576; int tb = j >> 14; int r = j & 16383;
        src = ((tb == 0) ? Wt1 : (tb == 1) ? Wt2 : Wt3) + r; dst = Wtc + j;
    } else if (i8 < 24576 + 49152 + 32768){
        int j = i8 - 73728; src = Ws1 + j; dst = Ws1b + j;
    } else {
        int j = i8 - 106496; src = Ws2 + j; dst = Ws2b + j;
    }
    *(uint4*)dst = pack8(src);
    if (t < 384){
        int tb2 = t >> 7, ch2 = t & 127;
        const float* bsrc = (tb2 == 0) ? bd1 : ((tb2 == 1) ? bd2 : bd3);
        bdcat[t] = bsrc[ch2];
    }
}

// ---------------------------------------------------------------- CSR build
__global__ void k_count(const int* __restrict__ ei, int* __restrict__ counts){
    int e = blockIdx.x * 256 + threadIdx.x;
    if (e < NE) atomicAdd(&counts[ei[e]], 1);
}

__global__ __launch_bounds__(1024) void k_scan(
    const int* __restrict__ counts, int* __restrict__ offsets, int* __restrict__ cursor)
{
    __shared__ int s[1024];
    const int t = threadIdx.x;
    const int CH = 5;
    int base = t * CH;
    int loc[CH];
    int lsum = 0;
    #pragma unroll
    for (int u = 0; u < CH; u++){
        int i = base + u;
        int v = (i < NN) ? counts[i] : 0;
        loc[u] = lsum;
        lsum += v;
    }
    s[t] = lsum;
    __syncthreads();
    for (int d = 1; d < 1024; d <<= 1){
        int v = (t >= d) ? s[t - d] : 0;
        __syncthreads();
        s[t] += v;
        __syncthreads();
    }
    int excl = s[t] - lsum;
    #pragma unroll
    for (int u = 0; u < CH; u++){
        int i = base + u;
        if (i < NN){ int o = excl + loc[u]; offsets[i] = o; cursor[i] = o; }
    }
    if (t == 1023) offsets[NN] = s[1023];
}

__global__ void k_fill(const int* __restrict__ ei, const int* __restrict__ z,
                       const float* __restrict__ ew, const float* __restrict__ evn,
                       int* __restrict__ cursor, int* __restrict__ elist,
                       float2* __restrict__ meta, float* __restrict__ evn_p){
    int e = blockIdx.x * 256 + threadIdx.x;
    if (e < NE){
        int sN = ei[e], dN = ei[NE + e];
        int p = atomicAdd(&cursor[sN], 1);
        elist[p] = e;
        float w = ew[e];
        float c = (w < 5.0f) ? 0.5f * (__cosf(w * PI_OVER_5) + 1.0f) : 0.0f;
        meta[p] = make_float2(c, __int_as_float(z[sN] | (z[dN] << 8)));
        evn_p[p*3+0] = evn[e*3+0];
        evn_p[p*3+1] = evn[e*3+1];
        evn_p[p*3+2] = evn[e*3+2];
    }
}

// ---------------------------------------------------------------- edge MFMA
// out[ch=384][e] = Wcat @ attr^T ; f_t[p][ch] = (out+bd) * cut*(embL[zs]+embR[zd]+b_emb2)
__global__ __launch_bounds__(256) void k_edge(
    const float* __restrict__ attr, const int* __restrict__ elist,
    const float2* __restrict__ meta,
    const bf16_t* __restrict__ Wcat, const float* __restrict__ bdcat,
    const float* __restrict__ embL, const float* __restrict__ embR,
    const float* __restrict__ b_emb2,
    bf16_t* __restrict__ f1, bf16_t* __restrict__ f2, bf16_t* __restrict__ f3)
{
    __shared__ __align__(16) bf16_t sB[64 * 72];   // 144B row stride
    __shared__ float sCut[64];
    __shared__ int   sZ[64];

    const int tid = threadIdx.x;
    const int p0  = blockIdx.x * 64;

    // stage attr tile via elist, fp32 -> bf16 (each thread: 16 floats)
    {
        int r = tid >> 2, qt = tid & 3;
        int e = elist[p0 + r];
        const float* ar = attr + (size_t)e * NRBF + qt * 16;
        uint4 o0 = pack8(ar);
        uint4 o1 = pack8(ar + 8);
        *(uint4*)&sB[r * 72 + qt * 16]     = o0;
        *(uint4*)&sB[r * 72 + qt * 16 + 8] = o1;
    }
    if (tid < 64){
        float2 m = meta[p0 + tid];
        sCut[tid] = m.x;
        sZ[tid]   = __float_as_int(m.y);
    }
    __syncthreads();

    const int wv = tid >> 6, lane = tid & 63;
    const int col = lane & 15, q = lane >> 4;

    floatx4 acc[6][4];
    #pragma unroll
    for (int mt = 0; mt < 6; mt++)
        #pragma unroll
        for (int nt = 0; nt < 4; nt++)
            acc[mt][nt] = (floatx4)(0.f);

    #pragma unroll
    for (int s = 0; s < 2; s++){
        short8 bf[4];
        #pragma unroll
        for (int nt = 0; nt < 4; nt++){
            int r = nt * 16 + col;
            bf[nt] = *(const short8*)&sB[r * 72 + s * 32 + q * 8];
        }
        short8 af[6];
        #pragma unroll
        for (int t = 0; t < 3; t++)
            #pragma unroll
            for (int c = 0; c < 2; c++){
                int m = t * 128 + wv * 32 + c * 16 + col;
                af[t * 2 + c] = *(const short8*)(Wcat + (size_t)m * NRBF + s * 32 + q * 8);
            }
        #pragma unroll
        for (int mt = 0; mt < 6; mt++)
            #pragma unroll
            for (int nt = 0; nt < 4; nt++)
                acc[mt][nt] = __builtin_amdgcn_mfma_f32_16x16x32_bf16(
                    af[mt], bf[nt], acc[mt][nt], 0, 0, 0);
    }

    floatx4 be[2], bd[3][2];
    #pragma unroll
    for (int c = 0; c < 2; c++){
        int ch4 = wv * 32 + c * 16 + q * 4;
        be[c] = *(const floatx4*)(b_emb2 + ch4);
        #pragma unroll
        for (int t = 0; t < 3; t++)
            bd[t][c] = *(const floatx4*)(bdcat + t * 128 + ch4);
    }
    bf16_t* const fs[3] = {f1, f2, f3};
    #pragma unroll
    for (int nt = 0; nt < 4; nt++){
        int e = nt * 16 + col;
        float cut = sCut[e];
        int zp = sZ[e];
        int zs = zp & 255, zd = zp >> 8;
        size_t orow = (size_t)(p0 + e) * HID;
        #pragma unroll
        for (int c = 0; c < 2; c++){
            int ch4 = wv * 32 + c * 16 + q * 4;
            floatx4 L = *(const floatx4*)(embL + zs * HID + ch4);
            floatx4 R = *(const floatx4*)(embR + zd * HID + ch4);
            floatx4 Cv = (L + R + be[c]) * cut;
            #pragma unroll
            for (int t = 0; t < 3; t++){
                floatx4 v = (acc[t * 2 + c][nt] + bd[t][c]) * Cv;
                uint2 pk;
                pk.x = to_bf16(v[0]) | ((unsigned)to_bf16(v[1]) << 16);
                pk.y = to_bf16(v[2]) | ((unsigned)to_bf16(v[3]) << 16);
                *(uint2*)(fs[t] + orow + ch4) = pk;
            }
        }
    }
}

// ---------------------------------------------------------------- gather + LN
// acc planes (bf16): 0:c 1:ax 2:ay 3:az 4:sxx 5:syy 6:szz 7:sxy 8:sxz 9:syz
__global__ __launch_bounds__(128) void k_gather(
    const int* __restrict__ offsets, const float* __restrict__ evn_p,
    const bf16_t* __restrict__ f1, const bf16_t* __restrict__ f2, const bf16_t* __restrict__ f3,
    const float* __restrict__ ln_g, const float* __restrict__ ln_b,
    bf16_t* __restrict__ acc, bf16_t* __restrict__ ln_out)
{
    const int n = blockIdx.x, h = threadIdx.x;
    const int s = offsets[n], e_end = offsets[n + 1];
    float c=0, ax=0, ay=0, az=0, sxx=0, syy=0, szz=0, sxy=0, sxz=0, syz=0;
    for (int idx = s; idx < e_end; idx++){
        float vx = evn_p[idx*3+0], vy = evn_p[idx*3+1], vz = evn_p[idx*3+2];
        float t3 = (vx*vx + vy*vy + vz*vz) * (1.f/3.f);
        float a = from_bf16(f1[(size_t)idx * HID + h]);
        float b = from_bf16(f2[(size_t)idx * HID + h]);
        float d = from_bf16(f3[(size_t)idx * HID + h]);
        c += a;
        ax += b * vx; ay += b * vy; az += b * vz;
        sxx += d * (vx*vx - t3); syy += d * (vy*vy - t3); szz += d * (vz*vz - t3);
        sxy += d * (vx*vy); sxz += d * (vx*vz); syz += d * (vy*vz);
    }
    const int PS = NP * HID;
    const int base = n * HID + h;
    acc[0*PS+base]=to_bf16(c);   acc[1*PS+base]=to_bf16(ax);
    acc[2*PS+base]=to_bf16(ay);  acc[3*PS+base]=to_bf16(az);
    acc[4*PS+base]=to_bf16(sxx); acc[5*PS+base]=to_bf16(syy);
    acc[6*PS+base]=to_bf16(szz); acc[7*PS+base]=to_bf16(sxy);
    acc[8*PS+base]=to_bf16(sxz); acc[9*PS+base]=to_bf16(syz);

    float tn = 3.f*c*c + 2.f*c*(sxx+syy+szz)
             + sxx*sxx + syy*syy + szz*szz
             + 2.f*(sxy*sxy + sxz*sxz + syz*syz)
             + 2.f*(ax*ax + ay*ay + az*az);

    __shared__ float r1[128], r2[128];
    r1[h] = tn; r2[h] = tn * tn;
    __syncthreads();
    for (int st = 64; st > 0; st >>= 1){
        if (h < st){ r1[h] += r1[h + st]; r2[h] += r2[h + st]; }
        __syncthreads();
    }
    float mu  = r1[0] * (1.f / HID);
    float var = r2[0] * (1.f / HID) - mu * mu;
    ln_out[base] = to_bf16((tn - mu) * rsqrtf(var + LN_EPS) * ln_g[h] + ln_b[h]);
}

// ---------------------------------------------------------------- fused node kernel
// per block: 16 nodes. MLP1(128->256,silu) -> MLP2(256->384,silu) -> 10-plane
// mix GEMM (acc_p @ Wt^T) -> combine with norm -> out. All GEMMs bf16 MFMA.
__global__ __launch_bounds__(256) void k_node(
    const bf16_t* __restrict__ lnb, const bf16_t* __restrict__ accb,
    const bf16_t* __restrict__ Ws1b, const float* __restrict__ bs1,
    const bf16_t* __restrict__ Ws2b, const float* __restrict__ bs2,
    const bf16_t* __restrict__ Wtc,
    float* __restrict__ out)
{
    __shared__ __align__(16) bf16_t h1s[16 * 280];   // 560B row stride (16B-mult)
    __shared__ float nrms[16 * 392];

    const int tid = threadIdx.x;
    const int wv = tid >> 6, lane = tid & 63;
    const int col = lane & 15, q = lane >> 4;
    const int n0 = blockIdx.x * 16;

    // ---- phase 1: h1 = silu(lnb @ Ws1^T + bs1), wave handles 64 cols
    {
        short8 a1[4];
        #pragma unroll
        for (int k = 0; k < 4; k++)
            a1[k] = *(const short8*)(lnb + (size_t)(n0 + col) * HID + k * 32 + q * 8);
        floatx4 c1[4];
        #pragma unroll
        for (int nt = 0; nt < 4; nt++) c1[nt] = (floatx4)(0.f);
        #pragma unroll
        for (int nt = 0; nt < 4; nt++){
            int cg = wv * 64 + nt * 16 + col;
            #pragma unroll
            for (int k = 0; k < 4; k++){
                short8 b = *(const short8*)(Ws1b + (size_t)cg * HID + k * 32 + q * 8);
                c1[nt] = __builtin_amdgcn_mfma_f32_16x16x32_bf16(a1[k], b, c1[nt], 0, 0, 0);
            }
        }
        #pragma unroll
        for (int nt = 0; nt < 4; nt++){
            int cg = wv * 64 + nt * 16 + col;
            float bias = bs1[cg];
            #pragma unroll
            for (int r = 0; r < 4; r++){
                float v = c1[nt][r] + bias;
                v = v / (1.f + __expf(-v));
                h1s[(q * 4 + r) * 280 + cg] = to_bf16(v);
            }
        }
    }
    __syncthreads();

    // ---- phase 2: norm = silu(h1 @ Ws2^T + bs2), wave handles 96 cols
    {
        short8 a2[8];
        #pragma unroll
        for (int k = 0; k < 8; k++)
            a2[k] = *(const short8*)&h1s[col * 280 + k * 32 + q * 8];
        floatx4 c2[6];
        #pragma unroll
        for (int nt = 0; nt < 6; nt++) c2[nt] = (floatx4)(0.f);
        #pragma unroll
        for (int nt = 0; nt < 6; nt++){
            int cg = wv * 96 + nt * 16 + col;
            #pragma unroll
            for (int k = 0; k < 8; k++){
                short8 b = *(const short8*)(Ws2b + (size_t)cg * 256 + k * 32 + q * 8);
                c2[nt] = __builtin_amdgcn_mfma_f32_16x16x32_bf16(a2[k], b, c2[nt], 0, 0, 0);
            }
        }
        #pragma unroll
        for (int nt = 0; nt < 6; nt++){
            int cg = wv * 96 + nt * 16 + col;
            float bias = bs2[cg];
            #pragma unroll
            for (int r = 0; r < 4; r++){
                float v = c2[nt][r] + bias;
                v = v / (1.f + __expf(-v));
                nrms[(q * 4 + r) * 392 + cg] = v;
            }
        }
    }
    __syncthreads();

    // ---- phase 3: 10-plane mix GEMM + combine; wave handles 32 g-cols
    floatx4 cm[10][2];
    #pragma unroll
    for (int p = 0; p < 10; p++){
        #pragma unroll
        for (int nt = 0; nt < 2; nt++) cm[p][nt] = (floatx4)(0.f);
    }
    #pragma unroll
    for (int p = 0; p < 10; p++){
        const bf16_t* ap = accb + (size_t)p * NP * HID + (size_t)(n0 + col) * HID;
        short8 a3[4];
        #pragma unroll
        for (int k = 0; k < 4; k++)
            a3[k] = *(const short8*)(ap + k * 32 + q * 8);
        int tb = (p == 0) ? 0 : ((p < 4) ? 1 : 2);
        #pragma unroll
        for (int nt = 0; nt < 2; nt++){
            int g = wv * 32 + nt * 16 + col;
            const bf16_t* wp = Wtc + tb * 16384 + (size_t)g * HID;
            #pragma unroll
            for (int k = 0; k < 4; k++){
                short8 b = *(const short8*)(wp + k * 32 + q * 8);
                cm[p][nt] = __builtin_amdgcn_mfma_f32_16x16x32_bf16(a3[k], b, cm[p][nt], 0, 0, 0);
            }
        }
    }
    #pragma unroll
    for (int nt = 0; nt < 2; nt++){
        int g = wv * 32 + nt * 16 + col;
        #pragma unroll
        for (int r = 0; r < 4; r++){
            int node = q * 4 + r;
            int n = n0 + node;
            if (n < NN){
                float n0f = nrms[node * 392 + g * 3 + 0];
                float n1f = nrms[node * 392 + g * 3 + 1];
                float n2f = nrms[node * 392 + g * 3 + 2];
                float c   = cm[0][nt][r];
                float ax  = cm[1][nt][r], ay = cm[2][nt][r], az = cm[3][nt][r];
                float sxx = cm[4][nt][r], syy= cm[5][nt][r], szz= cm[6][nt][r];
                float sxy = cm[7][nt][r], sxz= cm[8][nt][r], syz= cm[9][nt][r];
                float* o = out + ((size_t)n * HID + g) * 9;
                o[0] = n0f*c + n2f*sxx;   o[1] = n2f*sxy - n1f*az;  o[2] = n2f*sxz + n1f*ay;
                o[3] = n2f*sxy + n1f*az;  o[4] = n0f*c + n2f*syy;   o[5] = n2f*syz - n1f*ax;
                o[6] = n2f*sxz - n1f*ay;  o[7] = n2f*syz + n1f*ax;  o[8] = n0f*c + n2f*szz;
            }
        }
    }
}

// ---------------------------------------------------------------- launch
extern "C" void kernel_launch(void* const* d_in, const int* in_sizes, int n_in,
                              void* d_out, int out_size, void* d_ws, size_t ws_size,
                              hipStream_t stream)
{
    (void)in_sizes; (void)n_in; (void)out_size; (void)ws_size;
    const int*   z      = (const int*)  d_in[0];
    const int*   ei     = (const int*)  d_in[1];
    const float* ew     = (const float*)d_in[2];
    const float* evn    = (const float*)d_in[3];
    const float* attr   = (const float*)d_in[4];
    const float* emb    = (const float*)d_in[5];
    const float* W_emb2 = (const float*)d_in[6];
    const float* b_emb2 = (const float*)d_in[7];
    const float* Wd1 = (const float*)d_in[8];  const float* bd1 = (const float*)d_in[9];
    const float* Wd2 = (const float*)d_in[10]; const float* bd2 = (const float*)d_in[11];
    const float* Wd3 = (const float*)d_in[12]; const float* bd3 = (const float*)d_in[13];
    const float* Wt1 = (const float*)d_in[14]; const float* Wt2 = (const float*)d_in[15];
    const float* Wt3 = (const float*)d_in[16];
    const float* Ws1 = (const float*)d_in[17]; const float* bs1 = (const float*)d_in[18];
    const float* Ws2 = (const float*)d_in[19]; const float* bs2 = (const float*)d_in[20];
    const float* ln_g = (const float*)d_in[21]; const float* ln_b = (const float*)d_in[22];
    float* out = (float*)d_out;

    char* ws = (char*)d_ws;
    size_t o = 0;
    auto take = [&](size_t b)->size_t{ size_t c = o; o += (b + 255) & ~(size_t)255; return c; };
    size_t f1_o  = take((size_t)NE * HID * 2);
    size_t f2_o  = take((size_t)NE * HID * 2);
    size_t f3_o  = take((size_t)NE * HID * 2);
    size_t acc_o = take((size_t)10 * NP * HID * 2);
    size_t ln_of = take((size_t)NP * HID * 2);
    size_t eL_o  = take((size_t)128 * HID * 4);
    size_t eR_o  = take((size_t)128 * HID * 4);
    size_t cnt_o = take((size_t)NN * 4);
    size_t off_o = take((size_t)(NN + 1) * 4);
    size_t cur_o = take((size_t)NN * 4);
    size_t el_o  = take((size_t)NE * 4);
    size_t met_o = take((size_t)NE * 8);
    size_t evp_o = take((size_t)NE * 12);
    size_t wc_o  = take((size_t)384 * 64 * 2);
    size_t wt_o  = take((size_t)3 * 128 * 128 * 2);
    size_t w1_o  = take((size_t)256 * 128 * 2);
    size_t w2_o  = take((size_t)384 * 256 * 2);
    size_t bdc_o = take((size_t)384 * 4);

    bf16_t* f1 = (bf16_t*)(ws + f1_o);
    bf16_t* f2 = (bf16_t*)(ws + f2_o);
    bf16_t* f3 = (bf16_t*)(ws + f3_o);
    bf16_t* accb = (bf16_t*)(ws + acc_o);
    bf16_t* lnb  = (bf16_t*)(ws + ln_of);
    float* embL = (float*)(ws + eL_o);
    float* embR = (float*)(ws + eR_o);
    int* counts = (int*)(ws + cnt_o);
    int* offs   = (int*)(ws + off_o);
    int* cursor = (int*)(ws + cur_o);
    int* elist  = (int*)(ws + el_o);
    float2* meta = (float2*)(ws + met_o);
    float* evn_p = (float*)(ws + evp_o);
    bf16_t* Wcat = (bf16_t*)(ws + wc_o);
    bf16_t* Wtc  = (bf16_t*)(ws + wt_o);
    bf16_t* Ws1b = (bf16_t*)(ws + w1_o);
    bf16_t* Ws2b = (bf16_t*)(ws + w2_o);
    float* bdcat = (float*)(ws + bdc_o);

    hipMemsetAsync(counts, 0, (size_t)NN * 4, stream);

    k_prep_wts<<<100, 256, 0, stream>>>(Wd1, Wd2, Wd3, bd1, bd2, bd3,
                                        Wt1, Wt2, Wt3, Ws1, Ws2,
                                        Wcat, Wtc, Ws1b, Ws2b, bdcat);
    k_embtab<<<128, 128, 0, stream>>>(W_emb2, emb, embL, embR);
    k_count <<<(NE + 255) / 256, 256, 0, stream>>>(ei, counts);
    k_scan  <<<1, 1024, 0, stream>>>(counts, offs, cursor);
    k_fill  <<<(NE + 255) / 256, 256, 0, stream>>>(ei, z, ew, evn, cursor, elist, meta, evn_p);
    k_edge  <<<NE / 64, 256, 0, stream>>>(attr, elist, meta, Wcat, bdcat,
                                          embL, embR, b_emb2, f1, f2, f3);
    k_gather<<<NN, 128, 0, stream>>>(offs, evn_p, f1, f2, f3, ln_g, ln_b, accb, lnb);
    k_node  <<<(NN + 15) / 16, 256, 0, stream>>>(lnb, accb, Ws1b, bs1, Ws2b, bs2, Wtc, out);
}